// Round 10
// baseline (248.996 us; speedup 1.0000x reference)
//
#include <hip/hip_runtime.h>

// MultiHeadSelfAttention  B=2 S=2048 D=1024 H=16 d=64, fp32 in/out.
// R9: attn restructured for LDS throughput (R8 attn was LDS-pipe-bound:
//   4 waves re-read the same shared K/V tiles = 4x fragment redundancy,
//   ~123K LDS-cyc/CU = 51us of the 61us).
//   New attn: block = 64 q shared across waves (Q frags in registers),
//   128-key macro-iters, wave w owns keys w*32..+31 (private K/V frags),
//   l accumulated via ones-B-fragment MFMA, partial O/l reduced through
//   LDS at the end. LDS instr per unit work cut ~4x.
// GEMMs/prep/swizzle unchanged from R8 (512-thread GEMM blocks).
// ws: Ksw 8M @0 | val_h 8M @8M | wq_t 6M @16M | wo_t 2M @22M | qkv 24M @24M
//     | x_h 8M @48M (dead after GEMM1, overwritten by Vsw)

#define D_MODEL 1024
#define NHEAD   16
#define HDIM    64
#define SEQ     2048
#define BATCH   2
#define NTOK    (BATCH * SEQ)

typedef float    f32x4 __attribute__((ext_vector_type(4)));
typedef _Float16 f16x8 __attribute__((ext_vector_type(8)));
typedef _Float16 f16x4 __attribute__((ext_vector_type(4)));

#define GLOBAL_LOAD_LDS16(gptr, lptr)                                            \
    __builtin_amdgcn_global_load_lds(                                            \
        (const __attribute__((address_space(1))) unsigned int*)(gptr),           \
        (__attribute__((address_space(3))) unsigned int*)(lptr), 16, 0, 0)

// ---------------- prep: x->fp16, W_qkv^T, W_out^T (one launch) ----------------
__global__ __launch_bounds__(256) void prep_kernel(
    const float* __restrict__ x, _Float16* __restrict__ xh,
    const float* __restrict__ Wqkv, _Float16* __restrict__ wq_t,
    const float* __restrict__ Wout, _Float16* __restrict__ wo_t)
{
    const int bx = blockIdx.x;
    const int tid = threadIdx.x;
    if (bx < 4096) {
        const int i = (bx * 256 + tid) * 4;
        const float4 v = *(const float4*)&x[i];
        f16x4 hh;
        hh[0] = (_Float16)v.x; hh[1] = (_Float16)v.y;
        hh[2] = (_Float16)v.z; hh[3] = (_Float16)v.w;
        *(f16x4*)&xh[i] = hh;
        return;
    }
    __shared__ float ts[64][65];
    const float* W; _Float16* Wt; int N, n0, k0;
    if (bx < 4096 + 768) {
        const int local = bx - 4096;
        W = Wqkv; Wt = wq_t; N = 3072;
        n0 = (local % 48) * 64; k0 = (local / 48) * 64;
    } else {
        const int local = bx - 4864;
        W = Wout; Wt = wo_t; N = 1024;
        n0 = (local % 16) * 64; k0 = (local / 16) * 64;
    }
    {
        const int r = tid >> 2, c = (tid & 3) << 4;
        const float* src = W + (size_t)(k0 + r) * N + n0 + c;
        #pragma unroll
        for (int u = 0; u < 4; ++u)
            *(float4*)&ts[r][c + u * 4] = *(const float4*)&src[u * 4];
    }
    __syncthreads();
    {
        const int n = tid >> 2, kg = (tid & 3) << 4;
        f16x8 v0, v1;
        #pragma unroll
        for (int j = 0; j < 8; ++j) {
            v0[j] = (_Float16)ts[kg + j][n];
            v1[j] = (_Float16)ts[kg + 8 + j][n];
        }
        _Float16* dst = Wt + (size_t)(n0 + n) * D_MODEL + k0 + kg;
        *(f16x8*)&dst[0] = v0;
        *(f16x8*)&dst[8] = v1;
    }
}

// ---------------- GEMM1: 128x128 tile, BK=32, 512 threads (8 waves of 32x64) ----------------
__global__ __launch_bounds__(512) void gemm_qkv_kernel(
    const _Float16* __restrict__ A, const _Float16* __restrict__ Bt,
    const float* __restrict__ bias, _Float16* __restrict__ Cout,
    int M, int N, int K)
{
    __shared__ _Float16 lds[2][4096];
    const int tid = threadIdx.x;
    const int wave = tid >> 6, lane = tid & 63;
    const int quad = lane >> 4, l16 = lane & 15;
    const int m0 = blockIdx.y * 128, n0 = blockIdx.x * 128;
    const int wr = wave >> 1, wc = wave & 1;

    f32x4 acc[2][4] = {};

    const bool isA = wave < 4;
    const _Float16* gsrc = isA ? (A + (size_t)m0 * K) : (Bt + (size_t)n0 * K);
    _Float16* ldst = isA ? &lds[0][0] : &lds[1][0];
    const int sbase = (wave & 3) * 2;

    for (int k0 = 0; k0 < K; k0 += 32) {
        __syncthreads();
        #pragma unroll
        for (int j = 0; j < 2; ++j) {
            const int seg = sbase + j;
            const int chunk = seg >> 1;
            const int row = ((seg & 1) << 6) | lane;
            GLOBAL_LOAD_LDS16(gsrc + (size_t)row * K + k0 + chunk * 8, ldst + seg * 512);
        }
        __syncthreads();

        f16x8 a[2], b[4];
        #pragma unroll
        for (int mt = 0; mt < 2; ++mt)
            a[mt] = *(const f16x8*)&lds[0][quad * 1024 + (wr * 32 + mt * 16 + l16) * 8];
        #pragma unroll
        for (int nt = 0; nt < 4; ++nt)
            b[nt] = *(const f16x8*)&lds[1][quad * 1024 + (wc * 64 + nt * 16 + l16) * 8];
        #pragma unroll
        for (int mt = 0; mt < 2; ++mt)
            #pragma unroll
            for (int nt = 0; nt < 4; ++nt)
                acc[mt][nt] = __builtin_amdgcn_mfma_f32_16x16x32_f16(a[mt], b[nt], acc[mt][nt], 0, 0, 0);
    }

    #pragma unroll
    for (int nt = 0; nt < 4; ++nt) {
        const int col = n0 + wc * 64 + nt * 16 + l16;
        const float bv = bias[col];
        #pragma unroll
        for (int mt = 0; mt < 2; ++mt) {
            #pragma unroll
            for (int r = 0; r < 4; ++r) {
                const int row = m0 + wr * 32 + mt * 16 + quad * 4 + r;
                Cout[(size_t)row * N + col] = (_Float16)(acc[mt][nt][r] + bv);
            }
        }
    }
}

// ---------------- GEMM2: 128x64 tile, BK=32, 512 threads (8 waves of 32x32), fp32 out ----------------
__global__ __launch_bounds__(512) void gemm_out_kernel(
    const _Float16* __restrict__ A, const _Float16* __restrict__ Bt,
    const float* __restrict__ bias, float* __restrict__ Cout)
{
    const int K = D_MODEL, N = D_MODEL;
    __shared__ _Float16 ldsA[4096];
    __shared__ _Float16 ldsB[2048];
    const int tid = threadIdx.x;
    const int wave = tid >> 6, lane = tid & 63;
    const int quad = lane >> 4, l16 = lane & 15;
    const int m0 = blockIdx.y * 128, n0 = blockIdx.x * 64;
    const int wr = wave >> 1, wc = wave & 1;

    f32x4 acc[2][2] = {};

    for (int k0 = 0; k0 < K; k0 += 32) {
        __syncthreads();
        if (wave < 4) {
            #pragma unroll
            for (int j = 0; j < 2; ++j) {
                const int seg = wave * 2 + j;
                const int chunk = seg >> 1;
                const int row = ((seg & 1) << 6) | lane;
                GLOBAL_LOAD_LDS16(A + (size_t)(m0 + row) * K + k0 + chunk * 8, ldsA + seg * 512);
            }
        } else {
            const int seg = wave - 4;
            GLOBAL_LOAD_LDS16(Bt + (size_t)(n0 + lane) * K + k0 + seg * 8, ldsB + seg * 512);
        }
        __syncthreads();

        f16x8 a[2], b[2];
        #pragma unroll
        for (int mt = 0; mt < 2; ++mt)
            a[mt] = *(const f16x8*)&ldsA[quad * 1024 + (wr * 32 + mt * 16 + l16) * 8];
        #pragma unroll
        for (int nt = 0; nt < 2; ++nt)
            b[nt] = *(const f16x8*)&ldsB[quad * 512 + (wc * 32 + nt * 16 + l16) * 8];
        #pragma unroll
        for (int mt = 0; mt < 2; ++mt)
            #pragma unroll
            for (int nt = 0; nt < 2; ++nt)
                acc[mt][nt] = __builtin_amdgcn_mfma_f32_16x16x32_f16(a[mt], b[nt], acc[mt][nt], 0, 0, 0);
    }

    #pragma unroll
    for (int nt = 0; nt < 2; ++nt) {
        const int col = n0 + wc * 32 + nt * 16 + l16;
        const float bv = bias[col];
        #pragma unroll
        for (int mt = 0; mt < 2; ++mt) {
            #pragma unroll
            for (int r = 0; r < 4; ++r) {
                const int row = m0 + wr * 32 + mt * 16 + quad * 4 + r;
                Cout[(size_t)row * N + col] = acc[mt][nt][r] + bv;
            }
        }
    }
}

// ---------------- K,V slices of qkv -> swizzled MFMA-ready layouts ----------------
__global__ __launch_bounds__(256) void swizzle_kv_kernel(
    const _Float16* __restrict__ qkv,
    _Float16* __restrict__ Ksw, _Float16* __restrict__ Vsw)
{
    __shared__ _Float16 ts[64][72];
    const int tid = threadIdx.x;
    const int s0 = blockIdx.x * 64, h = blockIdx.y, b = blockIdx.z;
    const size_t hsz = (size_t)8 * SEQ * 8;
    _Float16* kh = Ksw + (size_t)(b * NHEAD + h) * hsz;
    _Float16* vh = Vsw + (size_t)(b * NHEAD + h) * hsz;

    {
        const int s = s0 + (tid >> 2);
        const int dg = (tid & 3) << 4;
        const _Float16* src = qkv + (size_t)(b * SEQ + s) * (3 * D_MODEL) + h * (3 * HDIM) + HDIM + dg;
        const f16x8 v0 = *(const f16x8*)&src[0];
        const f16x8 v1 = *(const f16x8*)&src[8];
        const int c0 = dg >> 3;
        *(f16x8*)&kh[((size_t)c0 * SEQ + s) * 8]       = v0;
        *(f16x8*)&kh[((size_t)(c0 + 1) * SEQ + s) * 8] = v1;
    }
    {
        const int s = tid >> 2, dg = (tid & 3) << 4;
        const _Float16* src = qkv + (size_t)(b * SEQ + s0 + s) * (3 * D_MODEL) + h * (3 * HDIM) + 2 * HDIM + dg;
        *(f16x8*)&ts[s][dg]     = *(const f16x8*)&src[0];
        *(f16x8*)&ts[s][dg + 8] = *(const f16x8*)&src[8];
    }
    __syncthreads();
    {
        const int d = tid >> 2, sg = (tid & 3) << 4;
        f16x8 v0, v1;
        #pragma unroll
        for (int j = 0; j < 8; ++j) { v0[j] = ts[sg + j][d]; v1[j] = ts[sg + 8 + j][d]; }
        const int cs0 = (s0 + sg) >> 3;
        *(f16x8*)&vh[((size_t)cs0 * HDIM + d) * 8]       = v0;
        *(f16x8*)&vh[((size_t)(cs0 + 1) * HDIM + d) * 8] = v1;
    }
}

// ---------------- attn v2: wave-private keys, shared 64-q tile ----------------
// Kst: [c=d/8 (8)][key 128][8]  16KB    Vst: [cs=key/8 (16)][d 64][8]  16KB
// Ps:  per-wave [q 64][key32 pad40]     4 x 5KB = 20KB
// Wave w owns keys w*32..+31 of each 128-key macro-iter (16 iters).
// Partial O (64q x 64d f32) + partial l per wave; LDS tree-reduce at end.
__global__ __launch_bounds__(256) void attn_mfma_kernel(
    const _Float16* __restrict__ qkv,
    const _Float16* __restrict__ Ksw, const _Float16* __restrict__ Vsw,
    _Float16* __restrict__ val)
{
    __shared__ _Float16 Kst[8 * 128 * 8];      // 16KB
    __shared__ _Float16 Vst[16 * 64 * 8];      // 16KB
    __shared__ _Float16 Ps[4 * 64 * 40];       // 20KB

    const int tid = threadIdx.x;
    const int wave = tid >> 6, lane = tid & 63;
    const int quad = lane >> 4, l16 = lane & 15;
    const int qt = blockIdx.x, h = blockIdx.y, b = blockIdx.z;
    const int q0 = qt * 64;
    const int wbase = wave * 32;               // this wave's key offset in the 128-tile

    const size_t hsz = (size_t)8 * SEQ * 8;
    const _Float16* kh = Ksw + (size_t)(b * NHEAD + h) * hsz;
    const _Float16* vh = Vsw + (size_t)(b * NHEAD + h) * hsz;

    // Q B-fragments for ALL 64 q rows (loop-invariant, in registers), scaled log2(e)/8
    f16x8 qf[4][2];
    #pragma unroll
    for (int nt = 0; nt < 4; ++nt) {
        const int row = q0 + nt * 16 + l16;
        const _Float16* src = qkv + (size_t)(b * SEQ + row) * (3 * D_MODEL) + h * (3 * HDIM) + quad * 8;
        const f16x8 t0 = *(const f16x8*)(src);
        const f16x8 t1 = *(const f16x8*)(src + 32);
        #pragma unroll
        for (int j = 0; j < 8; ++j) {
            qf[nt][0][j] = (_Float16)((float)t0[j] * 0.1803368802f);
            qf[nt][1][j] = (_Float16)((float)t1[j] * 0.1803368802f);
        }
    }

    f16x8 ones;
    #pragma unroll
    for (int j = 0; j < 8; ++j) ones[j] = (_Float16)1.0f;

    f32x4 acc[4][4] = {};      // O partial: [mtile(q) 4][nt(d) 4]; row=mtile*16+quad*4+r, col=nt*16+l16
    f32x4 lones[4] = {};       // l partial: row=mtile*16+quad*4+r (replicated over l16)

    _Float16* psw = Ps + wave * (64 * 40);

    for (int kt = 0; kt < SEQ / 128; ++kt) {
        __syncthreads();
        // stage 128-key K and V tiles: 32 segs of 1KB, 8 per wave
        #pragma unroll
        for (int j = 0; j < 4; ++j) {
            const int kseg = wave * 4 + j;              // 0..15: c = kseg>>1, half = kseg&1
            const int c = kseg >> 1, half = kseg & 1;
            GLOBAL_LOAD_LDS16(kh + ((size_t)c * SEQ + kt * 128 + half * 64 + lane) * 8,
                              Kst + ((c * 128) + half * 64 + lane) * 8);
            const int vs = wave * 4 + j;                // 0..15: key-chunk
            GLOBAL_LOAD_LDS16(vh + ((size_t)(kt * 16 + vs) * 64 + lane) * 8,
                              Vst + (vs * 64 + lane) * 8);
        }
        __syncthreads();

        // S^T = K Q^T over this wave's 32 keys: mt in {0,1} (16-key tiles)
        #pragma unroll
        for (int mt = 0; mt < 2; ++mt) {
            const int krow = wbase + mt * 16 + l16;
            const f16x8 kA0 = *(const f16x8*)&Kst[((quad * 128) + krow) * 8];
            const f16x8 kA1 = *(const f16x8*)&Kst[(((4 + quad) * 128) + krow) * 8];
            f32x4 s[4] = {};
            #pragma unroll
            for (int nt = 0; nt < 4; ++nt) {
                s[nt] = __builtin_amdgcn_mfma_f32_16x16x32_f16(kA0, qf[nt][0], s[nt], 0, 0, 0);
                s[nt] = __builtin_amdgcn_mfma_f32_16x16x32_f16(kA1, qf[nt][1], s[nt], 0, 0, 0);
            }
            // p = exp2(s); write P[q][key_local] (b64, 4 key-consecutive)
            #pragma unroll
            for (int nt = 0; nt < 4; ++nt) {
                const float p0 = __builtin_amdgcn_exp2f(s[nt][0]);
                const float p1 = __builtin_amdgcn_exp2f(s[nt][1]);
                const float p2 = __builtin_amdgcn_exp2f(s[nt][2]);
                const float p3 = __builtin_amdgcn_exp2f(s[nt][3]);
                uint2 w;
                w.x = __builtin_bit_cast(unsigned, __builtin_amdgcn_cvt_pkrtz(p0, p1));
                w.y = __builtin_bit_cast(unsigned, __builtin_amdgcn_cvt_pkrtz(p2, p3));
                *(uint2*)&psw[(nt * 16 + l16) * 40 + mt * 16 + quad * 4] = w;
            }
        }
        // intra-wave RAW on psw: same-wave DS ordering, no barrier

        // O += P @ V ; l += P @ 1   (k-dim = this wave's 32 keys)
        f16x8 vf[4];
        #pragma unroll
        for (int nt = 0; nt < 4; ++nt)
            vf[nt] = *(const f16x8*)&Vst[(((wave * 4 + quad) * 64) + nt * 16 + l16) * 8];
        #pragma unroll
        for (int mtile = 0; mtile < 4; ++mtile) {
            const f16x8 pA = *(const f16x8*)&psw[(mtile * 16 + l16) * 40 + quad * 8];
            #pragma unroll
            for (int nt = 0; nt < 4; ++nt)
                acc[mtile][nt] = __builtin_amdgcn_mfma_f32_16x16x32_f16(pA, vf[nt], acc[mtile][nt], 0, 0, 0);
            lones[mtile] = __builtin_amdgcn_mfma_f32_16x16x32_f16(pA, ones, lones[mtile], 0, 0, 0);
        }
    }

    // ---- reduce partial O/l across the 4 waves via LDS ----
    __syncthreads();
    float* sO = (float*)((wave & 1) ? Vst : Kst);       // [64 q][64 d] f32, 16KB
    float* sL = ((float*)Ps) + ((wave & 1) ? 64 : 0);   // [64 q] f32
    if (wave < 2) {
        #pragma unroll
        for (int mtile = 0; mtile < 4; ++mtile) {
            #pragma unroll
            for (int r = 0; r < 4; ++r) {
                const int row = mtile * 16 + quad * 4 + r;
                #pragma unroll
                for (int nt = 0; nt < 4; ++nt)
                    sO[row * 64 + nt * 16 + l16] = acc[mtile][nt][r];
                sL[row] = lones[mtile][r];              // replicated lanes write same value
            }
        }
    }
    __syncthreads();
    if (wave >= 2) {
        #pragma unroll
        for (int mtile = 0; mtile < 4; ++mtile) {
            #pragma unroll
            for (int r = 0; r < 4; ++r) {
                const int row = mtile * 16 + quad * 4 + r;
                #pragma unroll
                for (int nt = 0; nt < 4; ++nt)
                    sO[row * 64 + nt * 16 + l16] += acc[mtile][nt][r];
                sL[row] += lones[mtile][r];             // same value per replicated lane: safe
            }
        }
    }
    __syncthreads();
    // final: each wave writes 16 q rows
    {
        float* A0 = (float*)Kst; float* A1 = (float*)Vst;
        float* L = (float*)Ps;
        #pragma unroll
        for (int r = 0; r < 4; ++r) {
            const int row = wave * 16 + quad * 4 + r;
            const float lt = L[row] + L[64 + row];
            const float inv = 1.f / lt;
            _Float16* dst = val + (size_t)(b * SEQ + q0 + row) * D_MODEL + h * HDIM;
            #pragma unroll
            for (int c = 0; c < 4; ++c) {
                const int col = c * 16 + l16;
                dst[col] = (_Float16)((A0[row * 64 + col] + A1[row * 64 + col]) * inv);
            }
        }
    }
}

extern "C" void kernel_launch(void* const* d_in, const int* in_sizes, int n_in,
                              void* d_out, int out_size, void* d_ws, size_t ws_size,
                              hipStream_t stream)
{
    const float* x     = (const float*)d_in[0];
    const float* W_qkv = (const float*)d_in[1];
    const float* b_qkv = (const float*)d_in[2];
    const float* W_out = (const float*)d_in[3];
    const float* b_out = (const float*)d_in[4];

    char* ws = (char*)d_ws;
    _Float16* Ksw   = (_Float16*)ws;                      // [32][8][2048][8]  8 MiB
    _Float16* val_h = (_Float16*)(ws + (8u << 20));       // [4096][1024]      8 MiB
    _Float16* wq_t  = (_Float16*)(ws + (16u << 20));      // [3072][1024]      6 MiB
    _Float16* wo_t  = (_Float16*)(ws + (22u << 20));      // [1024][1024]      2 MiB
    _Float16* qkv_h = (_Float16*)(ws + (24u << 20));      // [4096][3072]     24 MiB
    _Float16* x_h   = (_Float16*)(ws + (48u << 20));      // [4096][1024]      8 MiB
    _Float16* Vsw   = (_Float16*)(ws + (48u << 20));      // overwrites dead x_h

    prep_kernel<<<5120, 256, 0, stream>>>(x, x_h, W_qkv, wq_t, W_out, wo_t);
    gemm_qkv_kernel<<<dim3(3 * D_MODEL / 128, NTOK / 128), 512, 0, stream>>>(
        x_h, wq_t, b_qkv, qkv_h, NTOK, 3 * D_MODEL, D_MODEL);
    swizzle_kv_kernel<<<dim3(SEQ / 64, NHEAD, BATCH), 256, 0, stream>>>(qkv_h, Ksw, Vsw);
    attn_mfma_kernel<<<dim3(SEQ / 64, NHEAD, BATCH), 256, 0, stream>>>(qkv_h, Ksw, Vsw, val_h);
    gemm_out_kernel<<<dim3(D_MODEL / 64, NTOK / 128), 512, 0, stream>>>(
        val_h, wo_t, b_out, (float*)d_out);
}